// Round 4
// baseline (149.344 us; speedup 1.0000x reference)
//
#include <hip/hip_runtime.h>
#include <stdint.h>

#define N_PIX 4096
#define NB 8

typedef __attribute__((ext_vector_type(8))) short short8;
typedef __attribute__((ext_vector_type(4))) float f32x4;
typedef __attribute__((ext_vector_type(16))) float f32x16;

#define SCL 0.18033688011112042f   // log2(e)/8
#define LOG2E 1.4426950408889634f

__device__ __forceinline__ short f2bf(float x){
  union { float f; uint32_t u; } a; a.f = x;
  uint32_t r = a.u + 0x7FFFu + ((a.u >> 16) & 1u);
  return (short)(r >> 16);
}
__device__ __forceinline__ float bf2f(short h){
  union { uint32_t u; float f; } a; a.u = ((uint32_t)(uint16_t)h) << 16; return a.f;
}
__device__ __forceinline__ uint32_t cvtpk(float lo, float hi){
  uint32_t r;
  asm("v_cvt_pk_bf16_f32 %0, %1, %2" : "=v"(r) : "v"(lo), "v"(hi));
  return r;
}
// exchanges: a[lanes 32..63] <-> b[lanes 0..31]
__device__ __forceinline__ void permswap(uint32_t &a, uint32_t &b){
  asm("v_permlane32_swap_b32 %0, %1" : "+v"(a), "+v"(b));
}
__device__ __forceinline__ float fexp2(float x){ return __builtin_amdgcn_exp2f(x); }
__device__ __forceinline__ float wredSum(float v){
  #pragma unroll
  for (int m = 1; m < 64; m <<= 1) v += __shfl_xor(v, m);
  return v;
}
__device__ __forceinline__ float wredMax(float v){
  #pragma unroll
  for (int m = 1; m < 64; m <<= 1) v = fmaxf(v, __shfl_xor(v, m));
  return v;
}

// ---------------- K0a: per-(b,c) spatial mean of x ----------------
__global__ __launch_bounds__(256) void k_xmean(const float* __restrict__ x, float* __restrict__ xm){
  int row = blockIdx.x;            // b*64 + c
  int tid = threadIdx.x;
  const float* xr = x + (size_t)row * N_PIX;
  float s = 0.f;
  #pragma unroll
  for (int i = 0; i < 16; i++) s += xr[tid + 256*i];
  s = wredSum(s);
  __shared__ float red[4];
  if ((tid & 63) == 0) red[tid >> 6] = s;
  __syncthreads();
  if (tid == 0) xm[row] = (red[0]+red[1]+red[2]+red[3]) * (1.0f / N_PIX);
}

// ---------------- K0b: qm = Wq xm + bq, km = Wk xm + bk ----------------
__global__ void k_means(const float* __restrict__ wq, const float* __restrict__ bq,
                        const float* __restrict__ wk, const float* __restrict__ bk,
                        const float* __restrict__ xm, float* __restrict__ qm, float* __restrict__ km){
  int b = blockIdx.x; int c = threadIdx.x;   // 64 threads
  float sq = 0.f, sk = 0.f;
  for (int cc = 0; cc < 64; cc++){
    float xv = xm[b*64 + cc];
    sq += wq[c*64 + cc] * xv;
    sk += wk[c*64 + cc] * xv;
  }
  qm[b*64 + c] = sq + bq[c];
  km[b*64 + c] = sk + bk[c];
}

// ---------------- K1: QKV 1x1-conv GEMM (MFMA) + whitening + unary logits ----------------
// Q: [B][N][64] bf16, whitened & pre-scaled by log2(e)/8
// K: [B][N][64] bf16, whitened (unscaled)
// V: [B][64][N] bf16
// u: [B][N] f32, u[n] = qm . (k[n]-km)
__global__ __launch_bounds__(256) void k_qkv(
    const float* __restrict__ x,
    const float* __restrict__ wq, const float* __restrict__ bq,
    const float* __restrict__ wk, const float* __restrict__ bk,
    const float* __restrict__ wv, const float* __restrict__ bv,
    const float* __restrict__ qm, const float* __restrict__ km,
    short* __restrict__ Q, short* __restrict__ K, short* __restrict__ V,
    float* __restrict__ u)
{
  int blk = blockIdx.x;
  int b  = blk >> 5;
  int n0 = (blk & 31) * 128;
  int tid = threadIdx.x;
  int w = tid >> 6, l = tid & 63, lr = l & 15, lg = l >> 4;
  const float* xb = x + (size_t)b * 64 * N_PIX;

  int ncol[2];
  ncol[0] = n0 + w*32 + lr;
  ncol[1] = ncol[0] + 16;

  // B-fragments from x (shared across the 3 matrices)
  short8 bx[2][2];
  #pragma unroll
  for (int tj = 0; tj < 2; tj++){
    #pragma unroll
    for (int kc = 0; kc < 2; kc++){
      short8 t;
      #pragma unroll
      for (int j = 0; j < 8; j++){
        int cp = kc*32 + lg*8 + j;
        t[j] = f2bf(xb[(size_t)cp * N_PIX + ncol[tj]]);
      }
      bx[tj][kc] = t;
    }
  }

  float qmv[4][4];
  #pragma unroll
  for (int ti = 0; ti < 4; ti++)
    #pragma unroll
    for (int r = 0; r < 4; r++)
      qmv[ti][r] = qm[b*64 + ti*16 + lg*4 + r];

  short* Qb = Q + (size_t)b * N_PIX * 64;
  short* Kb = K + (size_t)b * N_PIX * 64;
  short* Vb = V + (size_t)b * 64 * N_PIX;
  const f32x4 z4 = {0.f, 0.f, 0.f, 0.f};

  // ---------- Q ----------
  {
    short8 aw[4][2];
    #pragma unroll
    for (int ti = 0; ti < 4; ti++)
      #pragma unroll
      for (int kc = 0; kc < 2; kc++){
        const float* wr = wq + (ti*16 + lr)*64 + kc*32 + lg*8;
        short8 t;
        #pragma unroll
        for (int j = 0; j < 8; j++) t[j] = f2bf(wr[j]);
        aw[ti][kc] = t;
      }
    f32x4 acc[4][2];
    #pragma unroll
    for (int ti = 0; ti < 4; ti++)
      #pragma unroll
      for (int tj = 0; tj < 2; tj++){
        acc[ti][tj] = z4;
        #pragma unroll
        for (int kc = 0; kc < 2; kc++)
          acc[ti][tj] = __builtin_amdgcn_mfma_f32_16x16x32_bf16(aw[ti][kc], bx[tj][kc], acc[ti][tj], 0, 0, 0);
      }
    float adj[4][4];
    #pragma unroll
    for (int ti = 0; ti < 4; ti++)
      #pragma unroll
      for (int r = 0; r < 4; r++)
        adj[ti][r] = bq[ti*16 + lg*4 + r] - qmv[ti][r];
    #pragma unroll
    for (int ti = 0; ti < 4; ti++)
      #pragma unroll
      for (int tj = 0; tj < 2; tj++){
        float v0 = (acc[ti][tj][0] + adj[ti][0]) * SCL;
        float v1 = (acc[ti][tj][1] + adj[ti][1]) * SCL;
        float v2 = (acc[ti][tj][2] + adj[ti][2]) * SCL;
        float v3 = (acc[ti][tj][3] + adj[ti][3]) * SCL;
        uint32_t p0 = ((uint32_t)(uint16_t)f2bf(v1) << 16) | (uint16_t)f2bf(v0);
        uint32_t p1 = ((uint32_t)(uint16_t)f2bf(v3) << 16) | (uint16_t)f2bf(v2);
        uint32_t* qr = (uint32_t*)(Qb + (size_t)ncol[tj]*64);
        qr[ti*8 + lg*2]     = p0;
        qr[ti*8 + lg*2 + 1] = p1;
      }
  }

  // ---------- K (+ unary logits) ----------
  {
    short8 aw[4][2];
    #pragma unroll
    for (int ti = 0; ti < 4; ti++)
      #pragma unroll
      for (int kc = 0; kc < 2; kc++){
        const float* wr = wk + (ti*16 + lr)*64 + kc*32 + lg*8;
        short8 t;
        #pragma unroll
        for (int j = 0; j < 8; j++) t[j] = f2bf(wr[j]);
        aw[ti][kc] = t;
      }
    f32x4 acc[4][2];
    #pragma unroll
    for (int ti = 0; ti < 4; ti++)
      #pragma unroll
      for (int tj = 0; tj < 2; tj++){
        acc[ti][tj] = z4;
        #pragma unroll
        for (int kc = 0; kc < 2; kc++)
          acc[ti][tj] = __builtin_amdgcn_mfma_f32_16x16x32_bf16(aw[ti][kc], bx[tj][kc], acc[ti][tj], 0, 0, 0);
      }
    float adj[4][4];
    #pragma unroll
    for (int ti = 0; ti < 4; ti++)
      #pragma unroll
      for (int r = 0; r < 4; r++)
        adj[ti][r] = bk[ti*16 + lg*4 + r] - km[b*64 + ti*16 + lg*4 + r];
    float up[2] = {0.f, 0.f};
    #pragma unroll
    for (int ti = 0; ti < 4; ti++)
      #pragma unroll
      for (int tj = 0; tj < 2; tj++){
        float v0 = acc[ti][tj][0] + adj[ti][0];
        float v1 = acc[ti][tj][1] + adj[ti][1];
        float v2 = acc[ti][tj][2] + adj[ti][2];
        float v3 = acc[ti][tj][3] + adj[ti][3];
        up[tj] += qmv[ti][0]*v0 + qmv[ti][1]*v1 + qmv[ti][2]*v2 + qmv[ti][3]*v3;
        uint32_t p0 = ((uint32_t)(uint16_t)f2bf(v1) << 16) | (uint16_t)f2bf(v0);
        uint32_t p1 = ((uint32_t)(uint16_t)f2bf(v3) << 16) | (uint16_t)f2bf(v2);
        uint32_t* kr = (uint32_t*)(Kb + (size_t)ncol[tj]*64);
        kr[ti*8 + lg*2]     = p0;
        kr[ti*8 + lg*2 + 1] = p1;
      }
    #pragma unroll
    for (int tj = 0; tj < 2; tj++){
      float s = up[tj];
      s += __shfl_xor(s, 16);
      s += __shfl_xor(s, 32);
      if (lg == 0) u[(size_t)b*N_PIX + ncol[tj]] = s;
    }
  }

  // ---------- V ----------
  {
    short8 aw[4][2];
    #pragma unroll
    for (int ti = 0; ti < 4; ti++)
      #pragma unroll
      for (int kc = 0; kc < 2; kc++){
        const float* wr = wv + (ti*16 + lr)*64 + kc*32 + lg*8;
        short8 t;
        #pragma unroll
        for (int j = 0; j < 8; j++) t[j] = f2bf(wr[j]);
        aw[ti][kc] = t;
      }
    f32x4 acc[4][2];
    #pragma unroll
    for (int ti = 0; ti < 4; ti++)
      #pragma unroll
      for (int tj = 0; tj < 2; tj++){
        acc[ti][tj] = z4;
        #pragma unroll
        for (int kc = 0; kc < 2; kc++)
          acc[ti][tj] = __builtin_amdgcn_mfma_f32_16x16x32_bf16(aw[ti][kc], bx[tj][kc], acc[ti][tj], 0, 0, 0);
      }
    #pragma unroll
    for (int ti = 0; ti < 4; ti++)
      #pragma unroll
      for (int tj = 0; tj < 2; tj++){
        #pragma unroll
        for (int r = 0; r < 4; r++){
          float v = acc[ti][tj][r] + bv[ti*16 + lg*4 + r];
          Vb[(size_t)(ti*16 + lg*4 + r) * N_PIX + ncol[tj]] = f2bf(v);
        }
      }
  }
}

// ---------------- K2: unary softmax + out_unary ----------------
__global__ __launch_bounds__(256) void k_unary(const float* __restrict__ u, const short* __restrict__ V,
                                               float* __restrict__ ou){
  int b = blockIdx.x >> 6, c = blockIdx.x & 63;
  int tid = threadIdx.x, w = tid >> 6, l = tid & 63;
  const float* ub = u + (size_t)b * N_PIX;
  float mx = -1e30f;
  #pragma unroll
  for (int i = 0; i < 16; i++) mx = fmaxf(mx, ub[tid + 256*i]);
  mx = wredMax(mx);
  __shared__ float redm[4];
  if (l == 0) redm[w] = mx;
  __syncthreads();
  mx = fmaxf(fmaxf(redm[0], redm[1]), fmaxf(redm[2], redm[3]));
  const short* Vr = V + ((size_t)b*64 + c) * N_PIX;
  float ps = 0.f, vs = 0.f;
  #pragma unroll
  for (int i = 0; i < 16; i++){
    int m = tid + 256*i;
    float p = exp2f((ub[m] - mx) * LOG2E);
    ps += p;
    vs += p * bf2f(Vr[m]);
  }
  ps = wredSum(ps); vs = wredSum(vs);
  __shared__ float r1[4], r2[4];
  if (l == 0){ r1[w] = ps; r2[w] = vs; }
  __syncthreads();
  if (tid == 0) ou[b*64 + c] = (r2[0]+r2[1]+r2[2]+r2[3]) / (r1[0]+r1[1]+r1[2]+r1[3]);
}

// ---------------- K3: flash attention + epilogue (32x32 MFMA, in-register P,
//                      register-double-buffered K/V, XCD-affinity block map) ----
// b = blk & 7  ->  all blocks of batch b land on XCD b (dispatch round-robin),
// so each XCD's L2 holds exactly one batch's K+V (1 MB << 4 MB).
// Unroll-2 with named fragment sets A/B: iteration i+1's global loads are in
// flight while iteration i computes (register prefetch; dead tail prefetch is
// modulo-wrapped in-bounds).
#define LOADKV(AK, AV, kb) do {                                              \
    const short* kp_ = Kb + (size_t)((kb) + l31)*64 + hi*8;                  \
    AK[0] = *(const short8*)(kp_);                                           \
    AK[1] = *(const short8*)(kp_ + 16);                                      \
    AK[2] = *(const short8*)(kp_ + 32);                                      \
    AK[3] = *(const short8*)(kp_ + 48);                                      \
    const short* vp_ = Vb + (size_t)l31 * N_PIX + (kb) + hi*8;               \
    AV[0] = *(const short8*)(vp_);                                           \
    AV[1] = *(const short8*)(vp_ + 16);                                      \
    AV[2] = *(const short8*)(vp_ + (size_t)32*N_PIX);                        \
    AV[3] = *(const short8*)(vp_ + (size_t)32*N_PIX + 16);                   \
  } while(0)

#define COMPUTE(AK, AV) do {                                                 \
    f32x16 st = {};                                                          \
    st = __builtin_amdgcn_mfma_f32_32x32x16_bf16(AK[0], qf[0], st, 0, 0, 0); \
    st = __builtin_amdgcn_mfma_f32_32x32x16_bf16(AK[1], qf[1], st, 0, 0, 0); \
    st = __builtin_amdgcn_mfma_f32_32x32x16_bf16(AK[2], qf[2], st, 0, 0, 0); \
    st = __builtin_amdgcn_mfma_f32_32x32x16_bf16(AK[3], qf[3], st, 0, 0, 0); \
    {                                                                        \
      float p0=fexp2(st[0]), p1=fexp2(st[1]), p2=fexp2(st[2]), p3=fexp2(st[3]); \
      float p4=fexp2(st[4]), p5=fexp2(st[5]), p6=fexp2(st[6]), p7=fexp2(st[7]); \
      rs += ((p0+p1)+(p2+p3)) + ((p4+p5)+(p6+p7));                           \
      uint32_t a0=cvtpk(p0,p1), a1=cvtpk(p2,p3);                             \
      uint32_t b0=cvtpk(p4,p5), b1=cvtpk(p6,p7);                             \
      permswap(a0,b0); permswap(a1,b1);                                      \
      union { short8 s; uint32_t u[4]; } pa;                                 \
      pa.u[0]=a0; pa.u[1]=a1; pa.u[2]=b0; pa.u[3]=b1;                        \
      accA = __builtin_amdgcn_mfma_f32_32x32x16_bf16(pa.s, AV[0], accA, 0, 0, 0); \
      accB = __builtin_amdgcn_mfma_f32_32x32x16_bf16(pa.s, AV[2], accB, 0, 0, 0); \
    }                                                                        \
    {                                                                        \
      float p0=fexp2(st[8]),  p1=fexp2(st[9]),  p2=fexp2(st[10]), p3=fexp2(st[11]); \
      float p4=fexp2(st[12]), p5=fexp2(st[13]), p6=fexp2(st[14]), p7=fexp2(st[15]); \
      rs += ((p0+p1)+(p2+p3)) + ((p4+p5)+(p6+p7));                           \
      uint32_t a0=cvtpk(p0,p1), a1=cvtpk(p2,p3);                             \
      uint32_t b0=cvtpk(p4,p5), b1=cvtpk(p6,p7);                             \
      permswap(a0,b0); permswap(a1,b1);                                      \
      union { short8 s; uint32_t u[4]; } pb;                                 \
      pb.u[0]=a0; pb.u[1]=a1; pb.u[2]=b0; pb.u[3]=b1;                        \
      accA = __builtin_amdgcn_mfma_f32_32x32x16_bf16(pb.s, AV[1], accA, 0, 0, 0); \
      accB = __builtin_amdgcn_mfma_f32_32x32x16_bf16(pb.s, AV[3], accB, 0, 0, 0); \
    }                                                                        \
  } while(0)

__global__ __launch_bounds__(512, 2) void k_attn(
    const short* __restrict__ Q, const short* __restrict__ K, const short* __restrict__ V,
    const float* __restrict__ ou, const float* __restrict__ x, float* __restrict__ out)
{
  int blk = blockIdx.x;
  int b  = blk & 7;                 // XCD-affinity: batch b -> XCD b
  int q0 = (blk >> 3) << 6;
  int tid = threadIdx.x;
  int w = tid >> 6;                 // 0..7
  int l = tid & 63;
  int l31 = l & 31, hi = l >> 5;
  int qh = w & 1, kq = w >> 1;

  __shared__ short Opart[8][32][66];   // [wave][q_local][c] bf16 partials
  __shared__ float lW[8][32];          // [wave][q_local] partial row sums

  const short* Qb = Q + (size_t)b * N_PIX * 64;
  const short* Kb = K + (size_t)b * N_PIX * 64;
  const short* Vb = V + (size_t)b * 64 * N_PIX;

  // Q B-fragments: lane(q=l31, hi): channels m*16 + hi*8 + j
  short8 qf[4];
  #pragma unroll
  for (int m = 0; m < 4; m++)
    qf[m] = *(const short8*)(Qb + (size_t)(q0 + qh*32 + l31)*64 + m*16 + hi*8);

  f32x16 accA = {}, accB = {};
  float rs = 0.f;

  int kbase = kq << 10;             // 1024-key slice per wave pair
  short8 akA[4], avA[4], akB[4], avB[4];
  LOADKV(akA, avA, kbase);

  for (int it = 0; it < 32; it += 2){
    int kb1 = kbase + (((it + 1) << 5) & 1023);
    LOADKV(akB, avB, kb1);          // prefetch odd iter while even computes
    COMPUTE(akA, avA);
    int kb2 = kbase + (((it + 2) << 5) & 1023);   // wraps in-bounds on tail (dead)
    LOADKV(akA, avA, kb2);          // prefetch next even while odd computes
    COMPUTE(akB, avB);
  }

  // rs: lane(q,hi) has sum over its half of keys; combine hi halves
  rs += __shfl_xor(rs, 32);
  if (hi == 0) lW[w][l31] = rs;

  #pragma unroll
  for (int r = 0; r < 16; r++){
    int row = (r & 3) + 8*(r >> 2) + 4*hi;
    Opart[w][row][l31]      = f2bf(accA[r]);
    Opart[w][row][32 + l31] = f2bf(accB[r]);
  }
  __syncthreads();

  const float* xb = x + (size_t)b * 64 * N_PIX;
  float* ob = out + (size_t)b * 64 * N_PIX;
  #pragma unroll
  for (int i = 0; i < 8; i++){
    int idx = i*512 + tid;
    int c = idx >> 6, q = idx & 63;
    int qhh = q >> 5, ql = q & 31;
    float os = bf2f(Opart[qhh][ql][c]) + bf2f(Opart[qhh+2][ql][c])
             + bf2f(Opart[qhh+4][ql][c]) + bf2f(Opart[qhh+6][ql][c]);
    float lt = lW[qhh][ql] + lW[qhh+2][ql] + lW[qhh+4][ql] + lW[qhh+6][ql];
    size_t gi = (size_t)c * N_PIX + q0 + q;
    ob[gi] = xb[gi] + os / lt + ou[b*64 + c];
  }
}

extern "C" void kernel_launch(void* const* d_in, const int* in_sizes, int n_in,
                              void* d_out, int out_size, void* d_ws, size_t ws_size,
                              hipStream_t stream)
{
  (void)in_sizes; (void)n_in; (void)out_size; (void)ws_size;
  const float* x  = (const float*)d_in[0];
  const float* wq = (const float*)d_in[1];
  const float* bq = (const float*)d_in[2];
  const float* wk = (const float*)d_in[3];
  const float* bk = (const float*)d_in[4];
  const float* wv = (const float*)d_in[5];
  const float* bv = (const float*)d_in[6];
  float* out = (float*)d_out;

  char* ws = (char*)d_ws;
  short* Q  = (short*)(ws);                 // 8*4096*64 bf16 = 4 MiB
  short* K  = (short*)(ws + 4194304);       // 4 MiB
  short* V  = (short*)(ws + 8388608);       // 4 MiB
  float* u  = (float*)(ws + 12582912);      // 8*4096 f32 = 128 KiB
  float* xm = (float*)(ws + 12713984);      // 8*64 f32
  float* qm = (float*)(ws + 12716032);
  float* km = (float*)(ws + 12718080);
  float* ou = (float*)(ws + 12720128);

  k_xmean<<<dim3(512), dim3(256), 0, stream>>>(x, xm);
  k_means<<<dim3(8), dim3(64), 0, stream>>>(wq, bq, wk, bk, xm, qm, km);
  k_qkv<<<dim3(256), dim3(256), 0, stream>>>(x, wq, bq, wk, bk, wv, bv, qm, km, Q, K, V, u);
  k_unary<<<dim3(512), dim3(256), 0, stream>>>(u, V, ou);
  k_attn<<<dim3(512), dim3(512), 0, stream>>>(Q, K, V, ou, x, out);
}

// Round 5
// 101.068 us; speedup vs baseline: 1.4777x; 1.4777x over previous
//
#include <hip/hip_runtime.h>
#include <stdint.h>

#define N_PIX 4096
#define NB 8

typedef __attribute__((ext_vector_type(8))) short short8;
typedef __attribute__((ext_vector_type(4))) float f32x4;
typedef __attribute__((ext_vector_type(2))) uint32_t u32x2;

#define SCL 0.18033688011112042f   // log2(e)/8
#define LOG2E 1.4426950408889634f

__device__ __forceinline__ short f2bf(float x){
  union { float f; uint32_t u; } a; a.f = x;
  uint32_t r = a.u + 0x7FFFu + ((a.u >> 16) & 1u);
  return (short)(r >> 16);
}
__device__ __forceinline__ float bf2f(short h){
  union { uint32_t u; float f; } a; a.u = ((uint32_t)(uint16_t)h) << 16; return a.f;
}
__device__ __forceinline__ uint32_t cvtpk(float lo, float hi){
  uint32_t r;
  asm("v_cvt_pk_bf16_f32 %0, %1, %2" : "=v"(r) : "v"(lo), "v"(hi));
  return r;
}
__device__ __forceinline__ float fexp2(float x){ return __builtin_amdgcn_exp2f(x); }
__device__ __forceinline__ float wredSum(float v){
  #pragma unroll
  for (int m = 1; m < 64; m <<= 1) v += __shfl_xor(v, m);
  return v;
}
__device__ __forceinline__ float wredMax(float v){
  #pragma unroll
  for (int m = 1; m < 64; m <<= 1) v = fmaxf(v, __shfl_xor(v, m));
  return v;
}

// ---------------- K0a: per-(b,c) spatial mean of x ----------------
__global__ __launch_bounds__(256) void k_xmean(const float* __restrict__ x, float* __restrict__ xm){
  int row = blockIdx.x;            // b*64 + c
  int tid = threadIdx.x;
  const float* xr = x + (size_t)row * N_PIX;
  float s = 0.f;
  #pragma unroll
  for (int i = 0; i < 16; i++) s += xr[tid + 256*i];
  s = wredSum(s);
  __shared__ float red[4];
  if ((tid & 63) == 0) red[tid >> 6] = s;
  __syncthreads();
  if (tid == 0) xm[row] = (red[0]+red[1]+red[2]+red[3]) * (1.0f / N_PIX);
}

// ---------------- K0b: qm = Wq xm + bq, km = Wk xm + bk ----------------
__global__ void k_means(const float* __restrict__ wq, const float* __restrict__ bq,
                        const float* __restrict__ wk, const float* __restrict__ bk,
                        const float* __restrict__ xm, float* __restrict__ qm, float* __restrict__ km){
  int b = blockIdx.x; int c = threadIdx.x;   // 64 threads
  float sq = 0.f, sk = 0.f;
  for (int cc = 0; cc < 64; cc++){
    float xv = xm[b*64 + cc];
    sq += wq[c*64 + cc] * xv;
    sk += wk[c*64 + cc] * xv;
  }
  qm[b*64 + c] = sq + bq[c];
  km[b*64 + c] = sk + bk[c];
}

// ---------------- K1: QKV 1x1-conv GEMM (MFMA) + whitening + unary logits ----------------
// Q: [B][N][64] bf16, whitened & pre-scaled by log2(e)/8
// K: [B][N][64] bf16, whitened (unscaled)
// V: [B][64][N] bf16
// u: [B][N] f32, u[n] = qm . (k[n]-km)
__global__ __launch_bounds__(256) void k_qkv(
    const float* __restrict__ x,
    const float* __restrict__ wq, const float* __restrict__ bq,
    const float* __restrict__ wk, const float* __restrict__ bk,
    const float* __restrict__ wv, const float* __restrict__ bv,
    const float* __restrict__ qm, const float* __restrict__ km,
    short* __restrict__ Q, short* __restrict__ K, short* __restrict__ V,
    float* __restrict__ u)
{
  int blk = blockIdx.x;
  int b  = blk >> 5;
  int n0 = (blk & 31) * 128;
  int tid = threadIdx.x;
  int w = tid >> 6, l = tid & 63, lr = l & 15, lg = l >> 4;
  const float* xb = x + (size_t)b * 64 * N_PIX;

  int ncol[2];
  ncol[0] = n0 + w*32 + lr;
  ncol[1] = ncol[0] + 16;

  // B-fragments from x (shared across the 3 matrices)
  short8 bx[2][2];
  #pragma unroll
  for (int tj = 0; tj < 2; tj++){
    #pragma unroll
    for (int kc = 0; kc < 2; kc++){
      short8 t;
      #pragma unroll
      for (int j = 0; j < 8; j++){
        int cp = kc*32 + lg*8 + j;
        t[j] = f2bf(xb[(size_t)cp * N_PIX + ncol[tj]]);
      }
      bx[tj][kc] = t;
    }
  }

  float qmv[4][4];
  #pragma unroll
  for (int ti = 0; ti < 4; ti++)
    #pragma unroll
    for (int r = 0; r < 4; r++)
      qmv[ti][r] = qm[b*64 + ti*16 + lg*4 + r];

  short* Qb = Q + (size_t)b * N_PIX * 64;
  short* Kb = K + (size_t)b * N_PIX * 64;
  short* Vb = V + (size_t)b * 64 * N_PIX;
  const f32x4 z4 = {0.f, 0.f, 0.f, 0.f};

  // ---------- Q ----------
  {
    short8 aw[4][2];
    #pragma unroll
    for (int ti = 0; ti < 4; ti++)
      #pragma unroll
      for (int kc = 0; kc < 2; kc++){
        const float* wr = wq + (ti*16 + lr)*64 + kc*32 + lg*8;
        short8 t;
        #pragma unroll
        for (int j = 0; j < 8; j++) t[j] = f2bf(wr[j]);
        aw[ti][kc] = t;
      }
    f32x4 acc[4][2];
    #pragma unroll
    for (int ti = 0; ti < 4; ti++)
      #pragma unroll
      for (int tj = 0; tj < 2; tj++){
        acc[ti][tj] = z4;
        #pragma unroll
        for (int kc = 0; kc < 2; kc++)
          acc[ti][tj] = __builtin_amdgcn_mfma_f32_16x16x32_bf16(aw[ti][kc], bx[tj][kc], acc[ti][tj], 0, 0, 0);
      }
    float adj[4][4];
    #pragma unroll
    for (int ti = 0; ti < 4; ti++)
      #pragma unroll
      for (int r = 0; r < 4; r++)
        adj[ti][r] = bq[ti*16 + lg*4 + r] - qmv[ti][r];
    #pragma unroll
    for (int ti = 0; ti < 4; ti++)
      #pragma unroll
      for (int tj = 0; tj < 2; tj++){
        float v0 = (acc[ti][tj][0] + adj[ti][0]) * SCL;
        float v1 = (acc[ti][tj][1] + adj[ti][1]) * SCL;
        float v2 = (acc[ti][tj][2] + adj[ti][2]) * SCL;
        float v3 = (acc[ti][tj][3] + adj[ti][3]) * SCL;
        uint32_t p0 = ((uint32_t)(uint16_t)f2bf(v1) << 16) | (uint16_t)f2bf(v0);
        uint32_t p1 = ((uint32_t)(uint16_t)f2bf(v3) << 16) | (uint16_t)f2bf(v2);
        uint32_t* qr = (uint32_t*)(Qb + (size_t)ncol[tj]*64);
        qr[ti*8 + lg*2]     = p0;
        qr[ti*8 + lg*2 + 1] = p1;
      }
  }

  // ---------- K (+ unary logits) ----------
  {
    short8 aw[4][2];
    #pragma unroll
    for (int ti = 0; ti < 4; ti++)
      #pragma unroll
      for (int kc = 0; kc < 2; kc++){
        const float* wr = wk + (ti*16 + lr)*64 + kc*32 + lg*8;
        short8 t;
        #pragma unroll
        for (int j = 0; j < 8; j++) t[j] = f2bf(wr[j]);
        aw[ti][kc] = t;
      }
    f32x4 acc[4][2];
    #pragma unroll
    for (int ti = 0; ti < 4; ti++)
      #pragma unroll
      for (int tj = 0; tj < 2; tj++){
        acc[ti][tj] = z4;
        #pragma unroll
        for (int kc = 0; kc < 2; kc++)
          acc[ti][tj] = __builtin_amdgcn_mfma_f32_16x16x32_bf16(aw[ti][kc], bx[tj][kc], acc[ti][tj], 0, 0, 0);
      }
    float adj[4][4];
    #pragma unroll
    for (int ti = 0; ti < 4; ti++)
      #pragma unroll
      for (int r = 0; r < 4; r++)
        adj[ti][r] = bk[ti*16 + lg*4 + r] - km[b*64 + ti*16 + lg*4 + r];
    float up[2] = {0.f, 0.f};
    #pragma unroll
    for (int ti = 0; ti < 4; ti++)
      #pragma unroll
      for (int tj = 0; tj < 2; tj++){
        float v0 = acc[ti][tj][0] + adj[ti][0];
        float v1 = acc[ti][tj][1] + adj[ti][1];
        float v2 = acc[ti][tj][2] + adj[ti][2];
        float v3 = acc[ti][tj][3] + adj[ti][3];
        up[tj] += qmv[ti][0]*v0 + qmv[ti][1]*v1 + qmv[ti][2]*v2 + qmv[ti][3]*v3;
        uint32_t p0 = ((uint32_t)(uint16_t)f2bf(v1) << 16) | (uint16_t)f2bf(v0);
        uint32_t p1 = ((uint32_t)(uint16_t)f2bf(v3) << 16) | (uint16_t)f2bf(v2);
        uint32_t* kr = (uint32_t*)(Kb + (size_t)ncol[tj]*64);
        kr[ti*8 + lg*2]     = p0;
        kr[ti*8 + lg*2 + 1] = p1;
      }
    #pragma unroll
    for (int tj = 0; tj < 2; tj++){
      float s = up[tj];
      s += __shfl_xor(s, 16);
      s += __shfl_xor(s, 32);
      if (lg == 0) u[(size_t)b*N_PIX + ncol[tj]] = s;
    }
  }

  // ---------- V ----------
  {
    short8 aw[4][2];
    #pragma unroll
    for (int ti = 0; ti < 4; ti++)
      #pragma unroll
      for (int kc = 0; kc < 2; kc++){
        const float* wr = wv + (ti*16 + lr)*64 + kc*32 + lg*8;
        short8 t;
        #pragma unroll
        for (int j = 0; j < 8; j++) t[j] = f2bf(wr[j]);
        aw[ti][kc] = t;
      }
    f32x4 acc[4][2];
    #pragma unroll
    for (int ti = 0; ti < 4; ti++)
      #pragma unroll
      for (int tj = 0; tj < 2; tj++){
        acc[ti][tj] = z4;
        #pragma unroll
        for (int kc = 0; kc < 2; kc++)
          acc[ti][tj] = __builtin_amdgcn_mfma_f32_16x16x32_bf16(aw[ti][kc], bx[tj][kc], acc[ti][tj], 0, 0, 0);
      }
    #pragma unroll
    for (int ti = 0; ti < 4; ti++)
      #pragma unroll
      for (int tj = 0; tj < 2; tj++){
        #pragma unroll
        for (int r = 0; r < 4; r++){
          float v = acc[ti][tj][r] + bv[ti*16 + lg*4 + r];
          Vb[(size_t)(ti*16 + lg*4 + r) * N_PIX + ncol[tj]] = f2bf(v);
        }
      }
  }
}

// ---------------- K2: unary softmax + out_unary ----------------
__global__ __launch_bounds__(256) void k_unary(const float* __restrict__ u, const short* __restrict__ V,
                                               float* __restrict__ ou){
  int b = blockIdx.x >> 6, c = blockIdx.x & 63;
  int tid = threadIdx.x, w = tid >> 6, l = tid & 63;
  const float* ub = u + (size_t)b * N_PIX;
  float mx = -1e30f;
  #pragma unroll
  for (int i = 0; i < 16; i++) mx = fmaxf(mx, ub[tid + 256*i]);
  mx = wredMax(mx);
  __shared__ float redm[4];
  if (l == 0) redm[w] = mx;
  __syncthreads();
  mx = fmaxf(fmaxf(redm[0], redm[1]), fmaxf(redm[2], redm[3]));
  const short* Vr = V + ((size_t)b*64 + c) * N_PIX;
  float ps = 0.f, vs = 0.f;
  #pragma unroll
  for (int i = 0; i < 16; i++){
    int m = tid + 256*i;
    float p = exp2f((ub[m] - mx) * LOG2E);
    ps += p;
    vs += p * bf2f(Vr[m]);
  }
  ps = wredSum(ps); vs = wredSum(vs);
  __shared__ float r1[4], r2[4];
  if (l == 0){ r1[w] = ps; r2[w] = vs; }
  __syncthreads();
  if (tid == 0) ou[b*64 + c] = (r2[0]+r2[1]+r2[2]+r2[3]) / (r1[0]+r1[1]+r1[2]+r1[3]);
}

// ---------------- K3: flash attention + epilogue ----------------
// r2 structure (16x16 MFMA, cvt_pk pack, per-wave P-LDS) with:
//  - 8 waves/block (512 thr), each wave a 512-key slice (16 iters) -> 4 waves/SIMD
//  - XCD-affinity block map: b = blk & 7 (keeps each batch's K/V in one XCD L2)
__global__ __launch_bounds__(512, 2) void k_attn(
    const short* __restrict__ Q, const short* __restrict__ K, const short* __restrict__ V,
    const float* __restrict__ ou, const float* __restrict__ x, float* __restrict__ out)
{
  int blk = blockIdx.x;
  int b  = blk & 7;                 // XCD-affinity: batch b -> XCD b
  int q0 = (blk >> 3) << 6;
  int tid = threadIdx.x;
  int w = tid >> 6, l = tid & 63, lr = l & 15, lg = l >> 4;

  // LDS union: Pbuf (loop, 40 KB) vs Opart+lW (epilogue, 68 KB)
  __shared__ char smem[69632];
  short (*Pbuf)[64][40]  = (short(*)[64][40])smem;     // [wave][q][key 0..31 +pad]
  short (*Opart)[64][66] = (short(*)[64][66])smem;     // [wave][q][c] bf16 partials
  float (*lW)[64]        = (float(*)[64])(smem + 67584);

  const short* Qb = Q + (size_t)b * N_PIX * 64;
  const short* Kb = K + (size_t)b * N_PIX * 64;
  const short* Vb = V + (size_t)b * 64 * N_PIX;

  // Q as B-fragment (col = q), 4 q-tiles x 2 c-chains
  short8 bq[4][2];
  #pragma unroll
  for (int qt = 0; qt < 4; qt++)
    #pragma unroll
    for (int kc = 0; kc < 2; kc++)
      bq[qt][kc] = *(const short8*)(Qb + (size_t)(q0 + qt*16 + lr)*64 + kc*32 + lg*8);

  f32x4 acc[4][4];
  float rs[4];
  const f32x4 z4 = {0.f, 0.f, 0.f, 0.f};
  #pragma unroll
  for (int qt = 0; qt < 4; qt++){
    rs[qt] = 0.f;
    #pragma unroll
    for (int f = 0; f < 4; f++) acc[qt][f] = z4;
  }

  int kbase = w << 9;   // each of 8 waves owns 512 keys

  for (int it = 0; it < 16; ++it){
    int kb = kbase + (it << 5);
    // K as A-fragment (row = key): 2 key-tiles x 2 c-chains
    const short* krow0 = Kb + (size_t)(kb + lr)*64 + lg*8;
    const short* krow1 = krow0 + 16*64;
    short8 ak00 = *(const short8*)(krow0);
    short8 ak01 = *(const short8*)(krow0 + 32);
    short8 ak10 = *(const short8*)(krow1);
    short8 ak11 = *(const short8*)(krow1 + 32);
    short8 bv[4];
    #pragma unroll
    for (int f = 0; f < 4; f++)
      bv[f] = *(const short8*)(Vb + (size_t)(f*16 + lr)*N_PIX + kb + lg*8);

    #pragma unroll
    for (int qt = 0; qt < 4; qt++){
      // S^T tiles: D[key][q]
      f32x4 s0 = __builtin_amdgcn_mfma_f32_16x16x32_bf16(ak00, bq[qt][0], z4, 0, 0, 0);
      s0 = __builtin_amdgcn_mfma_f32_16x16x32_bf16(ak01, bq[qt][1], s0, 0, 0, 0);
      f32x4 s1 = __builtin_amdgcn_mfma_f32_16x16x32_bf16(ak10, bq[qt][0], z4, 0, 0, 0);
      s1 = __builtin_amdgcn_mfma_f32_16x16x32_bf16(ak11, bq[qt][1], s1, 0, 0, 0);
      float p00 = fexp2(s0[0]), p01 = fexp2(s0[1]), p02 = fexp2(s0[2]), p03 = fexp2(s0[3]);
      float p10 = fexp2(s1[0]), p11 = fexp2(s1[1]), p12 = fexp2(s1[2]), p13 = fexp2(s1[3]);
      rs[qt] += ((p00 + p01) + (p02 + p03)) + ((p10 + p11) + (p12 + p13));
      u32x2 w0, w1;
      w0[0] = cvtpk(p00, p01); w0[1] = cvtpk(p02, p03);   // keys 4lg..4lg+3   (tile 0)
      w1[0] = cvtpk(p10, p11); w1[1] = cvtpk(p12, p13);   // keys 16+4lg..+3   (tile 1)
      *(u32x2*)(&Pbuf[w][qt*16 + lr][lg*4])      = w0;
      *(u32x2*)(&Pbuf[w][qt*16 + lr][16 + lg*4]) = w1;
    }
    #pragma unroll
    for (int qt = 0; qt < 4; qt++){
      short8 ap = *(const short8*)(&Pbuf[w][qt*16 + lr][lg*8]);
      #pragma unroll
      for (int f = 0; f < 4; f++)
        acc[qt][f] = __builtin_amdgcn_mfma_f32_16x16x32_bf16(ap, bv[f], acc[qt][f], 0, 0, 0);
    }
  }

  // row sums: lane holds partial for q = qt*16+lr over its lg key-slice -> reduce over lg
  #pragma unroll
  for (int qt = 0; qt < 4; qt++){
    float v = rs[qt];
    v += __shfl_xor(v, 16);
    v += __shfl_xor(v, 32);
    rs[qt] = v;
  }

  __syncthreads();   // all waves done with Pbuf before Opart overwrites it

  if (lg == 0){
    #pragma unroll
    for (int qt = 0; qt < 4; qt++)
      lW[w][qt*16 + lr] = rs[qt];
  }
  #pragma unroll
  for (int qt = 0; qt < 4; qt++)
    #pragma unroll
    for (int f = 0; f < 4; f++)
      #pragma unroll
      for (int r = 0; r < 4; r++)
        Opart[w][qt*16 + lg*4 + r][f*16 + lr] = f2bf(acc[qt][f][r]);
  __syncthreads();

  const float* xb = x + (size_t)b * 64 * N_PIX;
  float* ob = out + (size_t)b * 64 * N_PIX;
  const float* oub = ou + b*64;
  #pragma unroll
  for (int i = 0; i < 8; i++){
    int idx = i*512 + tid;
    int c = idx >> 6, q = idx & 63;
    float os = 0.f, lt = 0.f;
    #pragma unroll
    for (int ww = 0; ww < 8; ww++){
      os += bf2f(Opart[ww][q][c]);
      lt += lW[ww][q];
    }
    size_t gi = (size_t)c * N_PIX + q0 + q;
    ob[gi] = xb[gi] + os / lt + oub[c];
  }
}

extern "C" void kernel_launch(void* const* d_in, const int* in_sizes, int n_in,
                              void* d_out, int out_size, void* d_ws, size_t ws_size,
                              hipStream_t stream)
{
  (void)in_sizes; (void)n_in; (void)out_size; (void)ws_size;
  const float* x  = (const float*)d_in[0];
  const float* wq = (const float*)d_in[1];
  const float* bq = (const float*)d_in[2];
  const float* wk = (const float*)d_in[3];
  const float* bk = (const float*)d_in[4];
  const float* wv = (const float*)d_in[5];
  const float* bv = (const float*)d_in[6];
  float* out = (float*)d_out;

  char* ws = (char*)d_ws;
  short* Q  = (short*)(ws);                 // 8*4096*64 bf16 = 4 MiB
  short* K  = (short*)(ws + 4194304);       // 4 MiB
  short* V  = (short*)(ws + 8388608);       // 4 MiB
  float* u  = (float*)(ws + 12582912);      // 8*4096 f32 = 128 KiB
  float* xm = (float*)(ws + 12713984);      // 8*64 f32
  float* qm = (float*)(ws + 12716032);
  float* km = (float*)(ws + 12718080);
  float* ou = (float*)(ws + 12720128);

  k_xmean<<<dim3(512), dim3(256), 0, stream>>>(x, xm);
  k_means<<<dim3(8), dim3(64), 0, stream>>>(wq, bq, wk, bk, xm, qm, km);
  k_qkv<<<dim3(256), dim3(256), 0, stream>>>(x, wq, bq, wk, bk, wv, bv, qm, km, Q, K, V, u);
  k_unary<<<dim3(512), dim3(256), 0, stream>>>(u, V, ou);
  k_attn<<<dim3(512), dim3(512), 0, stream>>>(Q, K, V, ou, x, out);
}

// Round 6
// 79.687 us; speedup vs baseline: 1.8741x; 1.2683x over previous
//
#include <hip/hip_runtime.h>
#include <stdint.h>

#define N_PIX 4096
#define NB 8

typedef __attribute__((ext_vector_type(8))) short short8;
typedef __attribute__((ext_vector_type(4))) float f32x4;
typedef __attribute__((ext_vector_type(2))) uint32_t u32x2;

#define SCL 0.18033688011112042f   // log2(e)/8
#define LOG2E 1.4426950408889634f

__device__ __forceinline__ short f2bf(float x){
  union { float f; uint32_t u; } a; a.f = x;
  uint32_t r = a.u + 0x7FFFu + ((a.u >> 16) & 1u);
  return (short)(r >> 16);
}
__device__ __forceinline__ float bf2f(short h){
  union { uint32_t u; float f; } a; a.u = ((uint32_t)(uint16_t)h) << 16; return a.f;
}
__device__ __forceinline__ uint32_t cvtpk(float lo, float hi){
  uint32_t r;
  asm("v_cvt_pk_bf16_f32 %0, %1, %2" : "=v"(r) : "v"(lo), "v"(hi));
  return r;
}
__device__ __forceinline__ float fexp2(float x){ return __builtin_amdgcn_exp2f(x); }
__device__ __forceinline__ float wredSum(float v){
  #pragma unroll
  for (int m = 1; m < 64; m <<= 1) v += __shfl_xor(v, m);
  return v;
}
__device__ __forceinline__ float wredMax(float v){
  #pragma unroll
  for (int m = 1; m < 64; m <<= 1) v = fmaxf(v, __shfl_xor(v, m));
  return v;
}

// ---------------- K0a: per-(b,c) spatial mean of x ----------------
__global__ __launch_bounds__(256) void k_xmean(const float* __restrict__ x, float* __restrict__ xm){
  int row = blockIdx.x;            // b*64 + c
  int tid = threadIdx.x;
  const float* xr = x + (size_t)row * N_PIX;
  float s = 0.f;
  #pragma unroll
  for (int i = 0; i < 16; i++) s += xr[tid + 256*i];
  s = wredSum(s);
  __shared__ float red[4];
  if ((tid & 63) == 0) red[tid >> 6] = s;
  __syncthreads();
  if (tid == 0) xm[row] = (red[0]+red[1]+red[2]+red[3]) * (1.0f / N_PIX);
}

// ---------------- K0b: qm = Wq xm + bq, km = Wk xm + bk ----------------
__global__ void k_means(const float* __restrict__ wq, const float* __restrict__ bq,
                        const float* __restrict__ wk, const float* __restrict__ bk,
                        const float* __restrict__ xm, float* __restrict__ qm, float* __restrict__ km){
  int b = blockIdx.x; int c = threadIdx.x;   // 64 threads
  float sq = 0.f, sk = 0.f;
  for (int cc = 0; cc < 64; cc++){
    float xv = xm[b*64 + cc];
    sq += wq[c*64 + cc] * xv;
    sk += wk[c*64 + cc] * xv;
  }
  qm[b*64 + c] = sq + bq[c];
  km[b*64 + c] = sk + bk[c];
}

// ---------------- K1: QKV 1x1-conv GEMM (MFMA) + whitening + unary logits ----------------
// Q : [B][N][64] bf16, whitened & pre-scaled by log2(e)/8 (row layout)
// Kf: [B][N/16][2 chain][64 lane][8] bf16 — pre-swizzled QK A-fragments
// Vf: [B][N/32][4 f][64 lane][8] bf16  — pre-swizzled PV B-fragments
// u : [B][N] f32, u[n] = qm . (k[n]-km)
__global__ __launch_bounds__(256) void k_qkv(
    const float* __restrict__ x,
    const float* __restrict__ wq, const float* __restrict__ bq,
    const float* __restrict__ wk, const float* __restrict__ bk,
    const float* __restrict__ wv, const float* __restrict__ bv,
    const float* __restrict__ qm, const float* __restrict__ km,
    short* __restrict__ Q, short* __restrict__ Kf, short* __restrict__ Vf,
    float* __restrict__ u)
{
  int blk = blockIdx.x;
  int b  = blk >> 5;
  int n0 = (blk & 31) * 128;
  int tid = threadIdx.x;
  int w = tid >> 6, l = tid & 63, lr = l & 15, lg = l >> 4;
  const float* xb = x + (size_t)b * 64 * N_PIX;

  int ncol[2];
  ncol[0] = n0 + w*32 + lr;
  ncol[1] = ncol[0] + 16;

  // B-fragments from x (shared across the 3 matrices)
  short8 bx[2][2];
  #pragma unroll
  for (int tj = 0; tj < 2; tj++){
    #pragma unroll
    for (int kc = 0; kc < 2; kc++){
      short8 t;
      #pragma unroll
      for (int j = 0; j < 8; j++){
        int cp = kc*32 + lg*8 + j;
        t[j] = f2bf(xb[(size_t)cp * N_PIX + ncol[tj]]);
      }
      bx[tj][kc] = t;
    }
  }

  float qmv[4][4];
  #pragma unroll
  for (int ti = 0; ti < 4; ti++)
    #pragma unroll
    for (int r = 0; r < 4; r++)
      qmv[ti][r] = qm[b*64 + ti*16 + lg*4 + r];

  short* Qb  = Q  + (size_t)b * N_PIX * 64;
  short* Kfb = Kf + (size_t)b * N_PIX * 64;
  short* Vfb = Vf + (size_t)b * N_PIX * 64;
  const f32x4 z4 = {0.f, 0.f, 0.f, 0.f};

  // ---------- Q ----------
  {
    short8 aw[4][2];
    #pragma unroll
    for (int ti = 0; ti < 4; ti++)
      #pragma unroll
      for (int kc = 0; kc < 2; kc++){
        const float* wr = wq + (ti*16 + lr)*64 + kc*32 + lg*8;
        short8 t;
        #pragma unroll
        for (int j = 0; j < 8; j++) t[j] = f2bf(wr[j]);
        aw[ti][kc] = t;
      }
    f32x4 acc[4][2];
    #pragma unroll
    for (int ti = 0; ti < 4; ti++)
      #pragma unroll
      for (int tj = 0; tj < 2; tj++){
        acc[ti][tj] = z4;
        #pragma unroll
        for (int kc = 0; kc < 2; kc++)
          acc[ti][tj] = __builtin_amdgcn_mfma_f32_16x16x32_bf16(aw[ti][kc], bx[tj][kc], acc[ti][tj], 0, 0, 0);
      }
    float adj[4][4];
    #pragma unroll
    for (int ti = 0; ti < 4; ti++)
      #pragma unroll
      for (int r = 0; r < 4; r++)
        adj[ti][r] = bq[ti*16 + lg*4 + r] - qmv[ti][r];
    #pragma unroll
    for (int ti = 0; ti < 4; ti++)
      #pragma unroll
      for (int tj = 0; tj < 2; tj++){
        float v0 = (acc[ti][tj][0] + adj[ti][0]) * SCL;
        float v1 = (acc[ti][tj][1] + adj[ti][1]) * SCL;
        float v2 = (acc[ti][tj][2] + adj[ti][2]) * SCL;
        float v3 = (acc[ti][tj][3] + adj[ti][3]) * SCL;
        uint32_t p0 = ((uint32_t)(uint16_t)f2bf(v1) << 16) | (uint16_t)f2bf(v0);
        uint32_t p1 = ((uint32_t)(uint16_t)f2bf(v3) << 16) | (uint16_t)f2bf(v2);
        uint32_t* qr = (uint32_t*)(Qb + (size_t)ncol[tj]*64);
        qr[ti*8 + lg*2]     = p0;
        qr[ti*8 + lg*2 + 1] = p1;
      }
  }

  // ---------- K -> Kf fragments (+ unary logits) ----------
  {
    short8 aw[4][2];
    #pragma unroll
    for (int ti = 0; ti < 4; ti++)
      #pragma unroll
      for (int kc = 0; kc < 2; kc++){
        const float* wr = wk + (ti*16 + lr)*64 + kc*32 + lg*8;
        short8 t;
        #pragma unroll
        for (int j = 0; j < 8; j++) t[j] = f2bf(wr[j]);
        aw[ti][kc] = t;
      }
    f32x4 acc[4][2];
    #pragma unroll
    for (int ti = 0; ti < 4; ti++)
      #pragma unroll
      for (int tj = 0; tj < 2; tj++){
        acc[ti][tj] = z4;
        #pragma unroll
        for (int kc = 0; kc < 2; kc++)
          acc[ti][tj] = __builtin_amdgcn_mfma_f32_16x16x32_bf16(aw[ti][kc], bx[tj][kc], acc[ti][tj], 0, 0, 0);
      }
    float adj[4][4];
    #pragma unroll
    for (int ti = 0; ti < 4; ti++)
      #pragma unroll
      for (int r = 0; r < 4; r++)
        adj[ti][r] = bk[ti*16 + lg*4 + r] - km[b*64 + ti*16 + lg*4 + r];
    float up[2] = {0.f, 0.f};
    #pragma unroll
    for (int ti = 0; ti < 4; ti++)
      #pragma unroll
      for (int tj = 0; tj < 2; tj++){
        float v0 = acc[ti][tj][0] + adj[ti][0];
        float v1 = acc[ti][tj][1] + adj[ti][1];
        float v2 = acc[ti][tj][2] + adj[ti][2];
        float v3 = acc[ti][tj][3] + adj[ti][3];
        up[tj] += qmv[ti][0]*v0 + qmv[ti][1]*v1 + qmv[ti][2]*v2 + qmv[ti][3]*v3;
        uint32_t p0 = ((uint32_t)(uint16_t)f2bf(v1) << 16) | (uint16_t)f2bf(v0);
        uint32_t p1 = ((uint32_t)(uint16_t)f2bf(v3) << 16) | (uint16_t)f2bf(v2);
        // Kf fragment store: c = ti*16+lg*4+r, n = ncol[tj]
        int n = ncol[tj];
        int di = (n >> 4)*512 + (ti >> 1)*256
               + ((n & 15) + 16*(2*(ti & 1) + (lg >> 1)))*4 + (lg & 1)*2;
        uint32_t* kr = (uint32_t*)Kfb;
        kr[di]     = p0;
        kr[di + 1] = p1;
      }
    #pragma unroll
    for (int tj = 0; tj < 2; tj++){
      float s = up[tj];
      s += __shfl_xor(s, 16);
      s += __shfl_xor(s, 32);
      if (lg == 0) u[(size_t)b*N_PIX + ncol[tj]] = s;
    }
  }

  // ---------- V -> Vf fragments ----------
  {
    short8 aw[4][2];
    #pragma unroll
    for (int ti = 0; ti < 4; ti++)
      #pragma unroll
      for (int kc = 0; kc < 2; kc++){
        const float* wr = wv + (ti*16 + lr)*64 + kc*32 + lg*8;
        short8 t;
        #pragma unroll
        for (int j = 0; j < 8; j++) t[j] = f2bf(wr[j]);
        aw[ti][kc] = t;
      }
    f32x4 acc[4][2];
    #pragma unroll
    for (int ti = 0; ti < 4; ti++)
      #pragma unroll
      for (int tj = 0; tj < 2; tj++){
        acc[ti][tj] = z4;
        #pragma unroll
        for (int kc = 0; kc < 2; kc++)
          acc[ti][tj] = __builtin_amdgcn_mfma_f32_16x16x32_bf16(aw[ti][kc], bx[tj][kc], acc[ti][tj], 0, 0, 0);
      }
    #pragma unroll
    for (int ti = 0; ti < 4; ti++)
      #pragma unroll
      for (int tj = 0; tj < 2; tj++){
        int n = ncol[tj];
        short* vr = Vfb + (n >> 5)*2048 + ti*512 + ((n & 31) >> 3)*128 + (n & 7);
        #pragma unroll
        for (int r = 0; r < 4; r++){
          float v = acc[ti][tj][r] + bv[ti*16 + lg*4 + r];
          vr[(lg*4 + r)*8] = f2bf(v);
        }
      }
  }
}

// ---------------- K2: unary softmax + out_unary (reads Vf) ----------------
__global__ __launch_bounds__(256) void k_unary(const float* __restrict__ u, const short* __restrict__ Vf,
                                               float* __restrict__ ou){
  int b = blockIdx.x >> 6, c = blockIdx.x & 63;
  int tid = threadIdx.x, w = tid >> 6, l = tid & 63;
  const float* ub = u + (size_t)b * N_PIX;
  float mx = -1e30f;
  #pragma unroll
  for (int i = 0; i < 16; i++) mx = fmaxf(mx, ub[tid + 256*i]);
  mx = wredMax(mx);
  __shared__ float redm[4];
  if (l == 0) redm[w] = mx;
  __syncthreads();
  mx = fmaxf(fmaxf(redm[0], redm[1]), fmaxf(redm[2], redm[3]));
  const short* Vfb = Vf + (size_t)b * N_PIX * 64;
  int f = c >> 4, lrc = c & 15;
  float ps = 0.f, vs = 0.f;
  #pragma unroll
  for (int i = 0; i < 2; i++){
    int t = i*256 + tid;                  // covers m = t*8 .. t*8+7
    const short8 v = *(const short8*)(Vfb + (t >> 2)*2048 + f*512 + (t & 3)*128 + lrc*8);
    #pragma unroll
    for (int j = 0; j < 8; j++){
      int m = t*8 + j;
      float p = exp2f((ub[m] - mx) * LOG2E);
      ps += p;
      vs += p * bf2f(v[j]);
    }
  }
  ps = wredSum(ps); vs = wredSum(vs);
  __shared__ float r1[4], r2[4];
  if (l == 0){ r1[w] = ps; r2[w] = vs; }
  __syncthreads();
  if (tid == 0) ou[b*64 + c] = (r2[0]+r2[1]+r2[2]+r2[3]) / (r1[0]+r1[1]+r1[2]+r1[3]);
}

// ---------------- K3: flash attention + epilogue ----------------
// 8 waves x 512-key slices over a 64-q tile. All loads coalesced from Kf/Vf.
// Pbuf: per-wave 4KB, 64B rows, XOR-swizzled (byte ^= (row&3)<<4) -> conflict-free.
// Epilogue: two-phase 4-wave Opart combine keeps LDS at 36KB (2 blocks/CU).
__global__ __launch_bounds__(512, 3) void k_attn(
    const short* __restrict__ Q, const short* __restrict__ Kf, const short* __restrict__ Vf,
    const float* __restrict__ ou, const float* __restrict__ x, float* __restrict__ out)
{
  int blk = blockIdx.x;
  int b  = blk & 7;                 // XCD-affinity: batch b -> XCD b
  int q0 = (blk >> 3) << 6;
  int tid = threadIdx.x;
  int w = tid >> 6, l = tid & 63, lr = l & 15, lg = l >> 4;

  __shared__ char smem[36864];
  short* Pw = (short*)(smem + w*4096);                 // per-wave swizzled P
  short (*Opart)[64][66] = (short(*)[64][66])smem;     // [4][64][66] bf16 (phases)
  float (*lW)[64] = (float(*)[64])(smem + 34816);      // [8][64]

  const short* Qb  = Q  + (size_t)b * N_PIX * 64;
  const short* Kfb = Kf + (size_t)b * N_PIX * 64;
  const short* Vfb = Vf + (size_t)b * N_PIX * 64;

  // Q as B-fragment (col = q), 4 q-tiles x 2 c-chains
  short8 bq[4][2];
  #pragma unroll
  for (int qt = 0; qt < 4; qt++)
    #pragma unroll
    for (int kc = 0; kc < 2; kc++)
      bq[qt][kc] = *(const short8*)(Qb + (size_t)(q0 + qt*16 + lr)*64 + kc*32 + lg*8);

  f32x4 acc[4][4];
  float rs[4];
  const f32x4 z4 = {0.f, 0.f, 0.f, 0.f};
  #pragma unroll
  for (int qt = 0; qt < 4; qt++){
    rs[qt] = 0.f;
    #pragma unroll
    for (int f = 0; f < 4; f++) acc[qt][f] = z4;
  }

  int kbase = w << 9;   // each of 8 waves owns 512 keys
  int sw = (lr & 3) << 4;          // row-swizzle bits (row = qt*16+lr -> row&3 = lr&3)

  for (int it = 0; it < 16; ++it){
    int kb = kbase + (it << 5);
    const short* kp = Kfb + (size_t)kb * 64 + l*8;   // fully coalesced 1KB frags
    short8 ak00 = *(const short8*)(kp);
    short8 ak01 = *(const short8*)(kp + 512);
    short8 ak10 = *(const short8*)(kp + 1024);
    short8 ak11 = *(const short8*)(kp + 1536);
    const short* vp = Vfb + (size_t)kb * 64 + l*8;
    short8 bv0 = *(const short8*)(vp);
    short8 bv1 = *(const short8*)(vp + 512);
    short8 bv2 = *(const short8*)(vp + 1024);
    short8 bv3 = *(const short8*)(vp + 1536);

    #pragma unroll
    for (int qt = 0; qt < 4; qt++){
      // S^T tiles: D[key][q]
      f32x4 s0 = __builtin_amdgcn_mfma_f32_16x16x32_bf16(ak00, bq[qt][0], z4, 0, 0, 0);
      s0 = __builtin_amdgcn_mfma_f32_16x16x32_bf16(ak01, bq[qt][1], s0, 0, 0, 0);
      f32x4 s1 = __builtin_amdgcn_mfma_f32_16x16x32_bf16(ak10, bq[qt][0], z4, 0, 0, 0);
      s1 = __builtin_amdgcn_mfma_f32_16x16x32_bf16(ak11, bq[qt][1], s1, 0, 0, 0);
      float p00 = fexp2(s0[0]), p01 = fexp2(s0[1]), p02 = fexp2(s0[2]), p03 = fexp2(s0[3]);
      float p10 = fexp2(s1[0]), p11 = fexp2(s1[1]), p12 = fexp2(s1[2]), p13 = fexp2(s1[3]);
      rs[qt] += ((p00 + p01) + (p02 + p03)) + ((p10 + p11) + (p12 + p13));
      u32x2 w0, w1;
      w0[0] = cvtpk(p00, p01); w0[1] = cvtpk(p02, p03);   // keys 4lg..4lg+3 (tile 0)
      w1[0] = cvtpk(p10, p11); w1[1] = cvtpk(p12, p13);   // keys 16+4lg..+3 (tile 1)
      char* base = (char*)Pw + (qt*16 + lr)*64;
      *(u32x2*)(base + ((lg*8) ^ sw))      = w0;
      *(u32x2*)(base + ((32 + lg*8) ^ sw)) = w1;
    }
    #pragma unroll
    for (int qt = 0; qt < 4; qt++){
      short8 ap = *(const short8*)((char*)Pw + (qt*16 + lr)*64 + ((lg*16) ^ sw));
      acc[qt][0] = __builtin_amdgcn_mfma_f32_16x16x32_bf16(ap, bv0, acc[qt][0], 0, 0, 0);
      acc[qt][1] = __builtin_amdgcn_mfma_f32_16x16x32_bf16(ap, bv1, acc[qt][1], 0, 0, 0);
      acc[qt][2] = __builtin_amdgcn_mfma_f32_16x16x32_bf16(ap, bv2, acc[qt][2], 0, 0, 0);
      acc[qt][3] = __builtin_amdgcn_mfma_f32_16x16x32_bf16(ap, bv3, acc[qt][3], 0, 0, 0);
    }
  }

  // row sums: reduce over lg groups
  #pragma unroll
  for (int qt = 0; qt < 4; qt++){
    float v = rs[qt];
    v += __shfl_xor(v, 16);
    v += __shfl_xor(v, 32);
    rs[qt] = v;
  }

  __syncthreads();   // all waves done with Pbuf

  if (lg == 0){
    #pragma unroll
    for (int qt = 0; qt < 4; qt++)
      lW[w][qt*16 + lr] = rs[qt];
  }
  // phase A: waves 0-3 deposit partial O
  if (w < 4){
    #pragma unroll
    for (int qt = 0; qt < 4; qt++)
      #pragma unroll
      for (int f = 0; f < 4; f++)
        #pragma unroll
        for (int r = 0; r < 4; r++)
          Opart[w][qt*16 + lg*4 + r][f*16 + lr] = f2bf(acc[qt][f][r]);
  }
  __syncthreads();

  float os[8];
  #pragma unroll
  for (int i = 0; i < 8; i++){
    int idx = i*512 + tid;
    int c = idx >> 6, q = idx & 63;
    os[i] = bf2f(Opart[0][q][c]) + bf2f(Opart[1][q][c])
          + bf2f(Opart[2][q][c]) + bf2f(Opart[3][q][c]);
  }
  __syncthreads();

  // phase B: waves 4-7 deposit
  if (w >= 4){
    #pragma unroll
    for (int qt = 0; qt < 4; qt++)
      #pragma unroll
      for (int f = 0; f < 4; f++)
        #pragma unroll
        for (int r = 0; r < 4; r++)
          Opart[w-4][qt*16 + lg*4 + r][f*16 + lr] = f2bf(acc[qt][f][r]);
  }
  __syncthreads();

  const float* xb = x + (size_t)b * 64 * N_PIX;
  float* ob = out + (size_t)b * 64 * N_PIX;
  const float* oub = ou + b*64;
  #pragma unroll
  for (int i = 0; i < 8; i++){
    int idx = i*512 + tid;
    int c = idx >> 6, q = idx & 63;
    float o2 = bf2f(Opart[0][q][c]) + bf2f(Opart[1][q][c])
             + bf2f(Opart[2][q][c]) + bf2f(Opart[3][q][c]);
    float lt = lW[0][q] + lW[1][q] + lW[2][q] + lW[3][q]
             + lW[4][q] + lW[5][q] + lW[6][q] + lW[7][q];
    size_t gi = (size_t)c * N_PIX + q0 + q;
    ob[gi] = xb[gi] + (os[i] + o2) / lt + oub[c];
  }
}

extern "C" void kernel_launch(void* const* d_in, const int* in_sizes, int n_in,
                              void* d_out, int out_size, void* d_ws, size_t ws_size,
                              hipStream_t stream)
{
  (void)in_sizes; (void)n_in; (void)out_size; (void)ws_size;
  const float* x  = (const float*)d_in[0];
  const float* wq = (const float*)d_in[1];
  const float* bq = (const float*)d_in[2];
  const float* wk = (const float*)d_in[3];
  const float* bk = (const float*)d_in[4];
  const float* wv = (const float*)d_in[5];
  const float* bv = (const float*)d_in[6];
  float* out = (float*)d_out;

  char* ws = (char*)d_ws;
  short* Q  = (short*)(ws);                 // 4 MiB
  short* Kf = (short*)(ws + 4194304);       // 4 MiB (fragment layout)
  short* Vf = (short*)(ws + 8388608);       // 4 MiB (fragment layout)
  float* u  = (float*)(ws + 12582912);      // 128 KiB
  float* xm = (float*)(ws + 12713984);
  float* qm = (float*)(ws + 12716032);
  float* km = (float*)(ws + 12718080);
  float* ou = (float*)(ws + 12720128);

  k_xmean<<<dim3(512), dim3(256), 0, stream>>>(x, xm);
  k_means<<<dim3(8), dim3(64), 0, stream>>>(wq, bq, wk, bk, xm, qm, km);
  k_qkv<<<dim3(256), dim3(256), 0, stream>>>(x, wq, bq, wk, bk, wv, bv, qm, km, Q, Kf, Vf, u);
  k_unary<<<dim3(512), dim3(256), 0, stream>>>(u, Vf, ou);
  k_attn<<<dim3(512), dim3(512), 0, stream>>>(Q, Kf, Vf, ou, x, out);
}

// Round 7
// 79.424 us; speedup vs baseline: 1.8803x; 1.0033x over previous
//
#include <hip/hip_runtime.h>
#include <stdint.h>

#define N_PIX 4096
#define NB 8

typedef __attribute__((ext_vector_type(8))) short short8;
typedef __attribute__((ext_vector_type(4))) float f32x4;
typedef __attribute__((ext_vector_type(2))) uint32_t u32x2;

#define SCL 0.18033688011112042f   // log2(e)/8
#define LOG2E 1.4426950408889634f

__device__ __forceinline__ short f2bf(float x){
  union { float f; uint32_t u; } a; a.f = x;
  uint32_t r = a.u + 0x7FFFu + ((a.u >> 16) & 1u);
  return (short)(r >> 16);
}
__device__ __forceinline__ float bf2f(short h){
  union { uint32_t u; float f; } a; a.u = ((uint32_t)(uint16_t)h) << 16; return a.f;
}
__device__ __forceinline__ uint32_t cvtpk(float lo, float hi){
  uint32_t r;
  asm("v_cvt_pk_bf16_f32 %0, %1, %2" : "=v"(r) : "v"(lo), "v"(hi));
  return r;
}
__device__ __forceinline__ float fexp2(float x){ return __builtin_amdgcn_exp2f(x); }
__device__ __forceinline__ float wredSum(float v){
  #pragma unroll
  for (int m = 1; m < 64; m <<= 1) v += __shfl_xor(v, m);
  return v;
}
__device__ __forceinline__ float wredMax(float v){
  #pragma unroll
  for (int m = 1; m < 64; m <<= 1) v = fmaxf(v, __shfl_xor(v, m));
  return v;
}

// ---------------- K0a: per-(b,c) spatial mean of x ----------------
__global__ __launch_bounds__(256) void k_xmean(const float* __restrict__ x, float* __restrict__ xm){
  int row = blockIdx.x;            // b*64 + c
  int tid = threadIdx.x;
  const float* xr = x + (size_t)row * N_PIX;
  float s = 0.f;
  #pragma unroll
  for (int i = 0; i < 16; i++) s += xr[tid + 256*i];
  s = wredSum(s);
  __shared__ float red[4];
  if ((tid & 63) == 0) red[tid >> 6] = s;
  __syncthreads();
  if (tid == 0) xm[row] = (red[0]+red[1]+red[2]+red[3]) * (1.0f / N_PIX);
}

// ---------------- K0b: qm = Wq xm + bq, km = Wk xm + bk ----------------
__global__ void k_means(const float* __restrict__ wq, const float* __restrict__ bq,
                        const float* __restrict__ wk, const float* __restrict__ bk,
                        const float* __restrict__ xm, float* __restrict__ qm, float* __restrict__ km){
  int b = blockIdx.x; int c = threadIdx.x;   // 64 threads
  float sq = 0.f, sk = 0.f;
  for (int cc = 0; cc < 64; cc++){
    float xv = xm[b*64 + cc];
    sq += wq[c*64 + cc] * xv;
    sk += wk[c*64 + cc] * xv;
  }
  qm[b*64 + c] = sq + bq[c];
  km[b*64 + c] = sk + bk[c];
}

// ---------------- K1: QKV 1x1-conv GEMM (MFMA) + whitening + unary logits ----------------
// Q : [B][N][64] bf16, whitened & pre-scaled by log2(e)/8 (row layout)
// Kf: [B][N/16][2 chain][64 lane][8] bf16 — pre-swizzled QK A-fragments
// Vf: [B][N/32][4 f][64 lane][8] bf16  — PV A-fragments (V^T), keys in pi-order:
//     slot j of lane-group lg maps to phys key: j<4 ? 4*lg+j : 16+4*lg+(j-4)
// u : [B][N] f32, u[n] = qm . (k[n]-km)
__global__ __launch_bounds__(256) void k_qkv(
    const float* __restrict__ x,
    const float* __restrict__ wq, const float* __restrict__ bq,
    const float* __restrict__ wk, const float* __restrict__ bk,
    const float* __restrict__ wv, const float* __restrict__ bv,
    const float* __restrict__ qm, const float* __restrict__ km,
    short* __restrict__ Q, short* __restrict__ Kf, short* __restrict__ Vf,
    float* __restrict__ u)
{
  int blk = blockIdx.x;
  int b  = blk >> 5;
  int n0 = (blk & 31) * 128;
  int tid = threadIdx.x;
  int w = tid >> 6, l = tid & 63, lr = l & 15, lg = l >> 4;
  const float* xb = x + (size_t)b * 64 * N_PIX;

  int ncol[2];
  ncol[0] = n0 + w*32 + lr;
  ncol[1] = ncol[0] + 16;

  // B-fragments from x (shared across the 3 matrices)
  short8 bx[2][2];
  #pragma unroll
  for (int tj = 0; tj < 2; tj++){
    #pragma unroll
    for (int kc = 0; kc < 2; kc++){
      short8 t;
      #pragma unroll
      for (int j = 0; j < 8; j++){
        int cp = kc*32 + lg*8 + j;
        t[j] = f2bf(xb[(size_t)cp * N_PIX + ncol[tj]]);
      }
      bx[tj][kc] = t;
    }
  }

  float qmv[4][4];
  #pragma unroll
  for (int ti = 0; ti < 4; ti++)
    #pragma unroll
    for (int r = 0; r < 4; r++)
      qmv[ti][r] = qm[b*64 + ti*16 + lg*4 + r];

  short* Qb  = Q  + (size_t)b * N_PIX * 64;
  short* Kfb = Kf + (size_t)b * N_PIX * 64;
  short* Vfb = Vf + (size_t)b * N_PIX * 64;
  const f32x4 z4 = {0.f, 0.f, 0.f, 0.f};

  // ---------- Q ----------
  {
    short8 aw[4][2];
    #pragma unroll
    for (int ti = 0; ti < 4; ti++)
      #pragma unroll
      for (int kc = 0; kc < 2; kc++){
        const float* wr = wq + (ti*16 + lr)*64 + kc*32 + lg*8;
        short8 t;
        #pragma unroll
        for (int j = 0; j < 8; j++) t[j] = f2bf(wr[j]);
        aw[ti][kc] = t;
      }
    f32x4 acc[4][2];
    #pragma unroll
    for (int ti = 0; ti < 4; ti++)
      #pragma unroll
      for (int tj = 0; tj < 2; tj++){
        acc[ti][tj] = z4;
        #pragma unroll
        for (int kc = 0; kc < 2; kc++)
          acc[ti][tj] = __builtin_amdgcn_mfma_f32_16x16x32_bf16(aw[ti][kc], bx[tj][kc], acc[ti][tj], 0, 0, 0);
      }
    float adj[4][4];
    #pragma unroll
    for (int ti = 0; ti < 4; ti++)
      #pragma unroll
      for (int r = 0; r < 4; r++)
        adj[ti][r] = bq[ti*16 + lg*4 + r] - qmv[ti][r];
    #pragma unroll
    for (int ti = 0; ti < 4; ti++)
      #pragma unroll
      for (int tj = 0; tj < 2; tj++){
        float v0 = (acc[ti][tj][0] + adj[ti][0]) * SCL;
        float v1 = (acc[ti][tj][1] + adj[ti][1]) * SCL;
        float v2 = (acc[ti][tj][2] + adj[ti][2]) * SCL;
        float v3 = (acc[ti][tj][3] + adj[ti][3]) * SCL;
        uint32_t p0 = ((uint32_t)(uint16_t)f2bf(v1) << 16) | (uint16_t)f2bf(v0);
        uint32_t p1 = ((uint32_t)(uint16_t)f2bf(v3) << 16) | (uint16_t)f2bf(v2);
        uint32_t* qr = (uint32_t*)(Qb + (size_t)ncol[tj]*64);
        qr[ti*8 + lg*2]     = p0;
        qr[ti*8 + lg*2 + 1] = p1;
      }
  }

  // ---------- K -> Kf fragments (+ unary logits) ----------
  {
    short8 aw[4][2];
    #pragma unroll
    for (int ti = 0; ti < 4; ti++)
      #pragma unroll
      for (int kc = 0; kc < 2; kc++){
        const float* wr = wk + (ti*16 + lr)*64 + kc*32 + lg*8;
        short8 t;
        #pragma unroll
        for (int j = 0; j < 8; j++) t[j] = f2bf(wr[j]);
        aw[ti][kc] = t;
      }
    f32x4 acc[4][2];
    #pragma unroll
    for (int ti = 0; ti < 4; ti++)
      #pragma unroll
      for (int tj = 0; tj < 2; tj++){
        acc[ti][tj] = z4;
        #pragma unroll
        for (int kc = 0; kc < 2; kc++)
          acc[ti][tj] = __builtin_amdgcn_mfma_f32_16x16x32_bf16(aw[ti][kc], bx[tj][kc], acc[ti][tj], 0, 0, 0);
      }
    float adj[4][4];
    #pragma unroll
    for (int ti = 0; ti < 4; ti++)
      #pragma unroll
      for (int r = 0; r < 4; r++)
        adj[ti][r] = bk[ti*16 + lg*4 + r] - km[b*64 + ti*16 + lg*4 + r];
    float up[2] = {0.f, 0.f};
    #pragma unroll
    for (int ti = 0; ti < 4; ti++)
      #pragma unroll
      for (int tj = 0; tj < 2; tj++){
        float v0 = acc[ti][tj][0] + adj[ti][0];
        float v1 = acc[ti][tj][1] + adj[ti][1];
        float v2 = acc[ti][tj][2] + adj[ti][2];
        float v3 = acc[ti][tj][3] + adj[ti][3];
        up[tj] += qmv[ti][0]*v0 + qmv[ti][1]*v1 + qmv[ti][2]*v2 + qmv[ti][3]*v3;
        uint32_t p0 = ((uint32_t)(uint16_t)f2bf(v1) << 16) | (uint16_t)f2bf(v0);
        uint32_t p1 = ((uint32_t)(uint16_t)f2bf(v3) << 16) | (uint16_t)f2bf(v2);
        // Kf fragment store: c = ti*16+lg*4+r, n = ncol[tj]
        int n = ncol[tj];
        int di = (n >> 4)*512 + (ti >> 1)*256
               + ((n & 15) + 16*(2*(ti & 1) + (lg >> 1)))*4 + (lg & 1)*2;
        uint32_t* kr = (uint32_t*)Kfb;
        kr[di]     = p0;
        kr[di + 1] = p1;
      }
    #pragma unroll
    for (int tj = 0; tj < 2; tj++){
      float s = up[tj];
      s += __shfl_xor(s, 16);
      s += __shfl_xor(s, 32);
      if (lg == 0) u[(size_t)b*N_PIX + ncol[tj]] = s;
    }
  }

  // ---------- V -> Vf fragments (V^T, pi key order) ----------
  {
    short8 aw[4][2];
    #pragma unroll
    for (int ti = 0; ti < 4; ti++)
      #pragma unroll
      for (int kc = 0; kc < 2; kc++){
        const float* wr = wv + (ti*16 + lr)*64 + kc*32 + lg*8;
        short8 t;
        #pragma unroll
        for (int j = 0; j < 8; j++) t[j] = f2bf(wr[j]);
        aw[ti][kc] = t;
      }
    f32x4 acc[4][2];
    #pragma unroll
    for (int ti = 0; ti < 4; ti++)
      #pragma unroll
      for (int tj = 0; tj < 2; tj++){
        acc[ti][tj] = z4;
        #pragma unroll
        for (int kc = 0; kc < 2; kc++)
          acc[ti][tj] = __builtin_amdgcn_mfma_f32_16x16x32_bf16(aw[ti][kc], bx[tj][kc], acc[ti][tj], 0, 0, 0);
      }
    // store: Vf[g*2048 + ti*512 + ((lr>>2)*16 + lg*4 + r)*8 + (lr&3) + 4*tj]
    //   (kk = n&31 = tj*16+lr; lane-group slot = lr>>2; j = (lr&3)+4*tj)
    #pragma unroll
    for (int ti = 0; ti < 4; ti++)
      #pragma unroll
      for (int tj = 0; tj < 2; tj++){
        int n = ncol[tj];
        short* vr = Vfb + (n >> 5)*2048 + ti*512 + ((lr >> 2)*16 + lg*4)*8 + (lr & 3) + 4*tj;
        #pragma unroll
        for (int r = 0; r < 4; r++){
          float v = acc[ti][tj][r] + bv[ti*16 + lg*4 + r];
          vr[r*8] = f2bf(v);
        }
      }
  }
}

// ---------------- K2: unary softmax + out_unary (reads pi-ordered Vf) ----------------
__global__ __launch_bounds__(256) void k_unary(const float* __restrict__ u, const short* __restrict__ Vf,
                                               float* __restrict__ ou){
  int b = blockIdx.x >> 6, c = blockIdx.x & 63;
  int tid = threadIdx.x, w = tid >> 6, l = tid & 63;
  const float* ub = u + (size_t)b * N_PIX;
  float mx = -1e30f;
  #pragma unroll
  for (int i = 0; i < 16; i++) mx = fmaxf(mx, ub[tid + 256*i]);
  mx = wredMax(mx);
  __shared__ float redm[4];
  if (l == 0) redm[w] = mx;
  __syncthreads();
  mx = fmaxf(fmaxf(redm[0], redm[1]), fmaxf(redm[2], redm[3]));
  const short* Vfb = Vf + (size_t)b * N_PIX * 64;
  int f = c >> 4, c15 = c & 15;
  int g = tid >> 1, h = tid & 1;   // thread covers group g, lane-slots 2h,2h+1
  float ps = 0.f, vs = 0.f;
  #pragma unroll
  for (int si = 0; si < 2; si++){
    int s = 2*h + si;
    const short8 v = *(const short8*)(Vfb + g*2048 + f*512 + (s*16 + c15)*8);
    #pragma unroll
    for (int j = 0; j < 8; j++){
      int kk = (j < 4) ? (4*s + j) : (16 + 4*s + (j - 4));
      int m = g*32 + kk;
      float p = exp2f((ub[m] - mx) * LOG2E);
      ps += p;
      vs += p * bf2f(v[j]);
    }
  }
  ps = wredSum(ps); vs = wredSum(vs);
  __shared__ float r1[4], r2[4];
  if (l == 0){ r1[w] = ps; r2[w] = vs; }
  __syncthreads();
  if (tid == 0) ou[b*64 + c] = (r2[0]+r2[1]+r2[2]+r2[3]) / (r1[0]+r1[1]+r1[2]+r1[3]);
}

// ---------------- K3: flash attention + epilogue ----------------
// Fully in-register main loop: swapped QK (S^T), exp2, cvt_pk -> P is directly a
// 16x16x32 B-fragment under pi key order; PV computes O^T = mfma(Vf, P, accT).
// No LDS / no shuffles in the loop. LDS only for the 8-way epilogue combine.
__global__ __launch_bounds__(512, 3) void k_attn(
    const short* __restrict__ Q, const short* __restrict__ Kf, const short* __restrict__ Vf,
    const float* __restrict__ ou, const float* __restrict__ x, float* __restrict__ out)
{
  int blk = blockIdx.x;
  int b  = blk & 7;                 // XCD-affinity: batch b -> XCD b
  int q0 = (blk >> 3) << 6;
  int tid = threadIdx.x;
  int w = tid >> 6, l = tid & 63, lr = l & 15, lg = l >> 4;

  __shared__ short Opart[8][64][66];   // [wave][q][c] bf16 partials
  __shared__ float lW[8][64];          // [wave][q] partial row sums

  const short* Qb  = Q  + (size_t)b * N_PIX * 64;
  const short* Kfb = Kf + (size_t)b * N_PIX * 64;
  const short* Vfb = Vf + (size_t)b * N_PIX * 64;

  // Q as B-fragment (col = q), 4 q-tiles x 2 c-chains
  short8 bq[4][2];
  #pragma unroll
  for (int qt = 0; qt < 4; qt++)
    #pragma unroll
    for (int kc = 0; kc < 2; kc++)
      bq[qt][kc] = *(const short8*)(Qb + (size_t)(q0 + qt*16 + lr)*64 + kc*32 + lg*8);

  f32x4 acc[4][4];      // acc[qt][f] = O^T[c-tile f][q-tile qt] partial
  float rs[4];
  const f32x4 z4 = {0.f, 0.f, 0.f, 0.f};
  #pragma unroll
  for (int qt = 0; qt < 4; qt++){
    rs[qt] = 0.f;
    #pragma unroll
    for (int f = 0; f < 4; f++) acc[qt][f] = z4;
  }

  int kbase = w << 9;   // each of 8 waves owns 512 keys

  for (int it = 0; it < 16; ++it){
    int kb = kbase + (it << 5);
    const short* kp = Kfb + (size_t)kb * 64 + l*8;   // coalesced 1KB frags
    short8 ak00 = *(const short8*)(kp);
    short8 ak01 = *(const short8*)(kp + 512);
    short8 ak10 = *(const short8*)(kp + 1024);
    short8 ak11 = *(const short8*)(kp + 1536);
    const short* vp = Vfb + (size_t)kb * 64 + l*8;
    short8 vf0 = *(const short8*)(vp);
    short8 vf1 = *(const short8*)(vp + 512);
    short8 vf2 = *(const short8*)(vp + 1024);
    short8 vf3 = *(const short8*)(vp + 1536);

    #pragma unroll
    for (int qt = 0; qt < 4; qt++){
      // S^T tiles: D[key][q]
      f32x4 s0 = __builtin_amdgcn_mfma_f32_16x16x32_bf16(ak00, bq[qt][0], z4, 0, 0, 0);
      s0 = __builtin_amdgcn_mfma_f32_16x16x32_bf16(ak01, bq[qt][1], s0, 0, 0, 0);
      f32x4 s1 = __builtin_amdgcn_mfma_f32_16x16x32_bf16(ak10, bq[qt][0], z4, 0, 0, 0);
      s1 = __builtin_amdgcn_mfma_f32_16x16x32_bf16(ak11, bq[qt][1], s1, 0, 0, 0);
      float p00 = fexp2(s0[0]), p01 = fexp2(s0[1]), p02 = fexp2(s0[2]), p03 = fexp2(s0[3]);
      float p10 = fexp2(s1[0]), p11 = fexp2(s1[1]), p12 = fexp2(s1[2]), p13 = fexp2(s1[3]);
      rs[qt] += ((p00 + p01) + (p02 + p03)) + ((p10 + p11) + (p12 + p13));
      union { short8 s; uint32_t u[4]; } pb;
      pb.u[0] = cvtpk(p00, p01);   // pi slots 0,1  (keys 4lg,4lg+1)
      pb.u[1] = cvtpk(p02, p03);   // slots 2,3     (keys 4lg+2,4lg+3)
      pb.u[2] = cvtpk(p10, p11);   // slots 4,5     (keys 16+4lg,16+4lg+1)
      pb.u[3] = cvtpk(p12, p13);   // slots 6,7     (keys 16+4lg+2,+3)
      acc[qt][0] = __builtin_amdgcn_mfma_f32_16x16x32_bf16(vf0, pb.s, acc[qt][0], 0, 0, 0);
      acc[qt][1] = __builtin_amdgcn_mfma_f32_16x16x32_bf16(vf1, pb.s, acc[qt][1], 0, 0, 0);
      acc[qt][2] = __builtin_amdgcn_mfma_f32_16x16x32_bf16(vf2, pb.s, acc[qt][2], 0, 0, 0);
      acc[qt][3] = __builtin_amdgcn_mfma_f32_16x16x32_bf16(vf3, pb.s, acc[qt][3], 0, 0, 0);
    }
  }

  // row sums: reduce over lg groups (q = qt*16 + lr)
  #pragma unroll
  for (int qt = 0; qt < 4; qt++){
    float v = rs[qt];
    v += __shfl_xor(v, 16);
    v += __shfl_xor(v, 32);
    rs[qt] = v;
  }

  if (lg == 0){
    #pragma unroll
    for (int qt = 0; qt < 4; qt++)
      lW[w][qt*16 + lr] = rs[qt];
  }
  // O^T deposit: acc[qt][f][r] = O^T[c = f*16+lg*4+r][q = qt*16+lr]
  #pragma unroll
  for (int qt = 0; qt < 4; qt++)
    #pragma unroll
    for (int f = 0; f < 4; f++)
      #pragma unroll
      for (int r = 0; r < 4; r++)
        Opart[w][qt*16 + lr][f*16 + lg*4 + r] = f2bf(acc[qt][f][r]);
  __syncthreads();

  const float* xb = x + (size_t)b * 64 * N_PIX;
  float* ob = out + (size_t)b * 64 * N_PIX;
  const float* oub = ou + b*64;
  #pragma unroll
  for (int i = 0; i < 8; i++){
    int idx = i*512 + tid;
    int c = idx >> 6, q = idx & 63;
    float os = 0.f, lt = 0.f;
    #pragma unroll
    for (int ww = 0; ww < 8; ww++){
      os += bf2f(Opart[ww][q][c]);
      lt += lW[ww][q];
    }
    size_t gi = (size_t)c * N_PIX + q0 + q;
    ob[gi] = xb[gi] + os / lt + oub[c];
  }
}

extern "C" void kernel_launch(void* const* d_in, const int* in_sizes, int n_in,
                              void* d_out, int out_size, void* d_ws, size_t ws_size,
                              hipStream_t stream)
{
  (void)in_sizes; (void)n_in; (void)out_size; (void)ws_size;
  const float* x  = (const float*)d_in[0];
  const float* wq = (const float*)d_in[1];
  const float* bq = (const float*)d_in[2];
  const float* wk = (const float*)d_in[3];
  const float* bk = (const float*)d_in[4];
  const float* wv = (const float*)d_in[5];
  const float* bv = (const float*)d_in[6];
  float* out = (float*)d_out;

  char* ws = (char*)d_ws;
  short* Q  = (short*)(ws);                 // 4 MiB
  short* Kf = (short*)(ws + 4194304);       // 4 MiB (fragment layout)
  short* Vf = (short*)(ws + 8388608);       // 4 MiB (V^T fragment layout, pi order)
  float* u  = (float*)(ws + 12582912);      // 128 KiB
  float* xm = (float*)(ws + 12713984);
  float* qm = (float*)(ws + 12716032);
  float* km = (float*)(ws + 12718080);
  float* ou = (float*)(ws + 12720128);

  k_xmean<<<dim3(512), dim3(256), 0, stream>>>(x, xm);
  k_means<<<dim3(8), dim3(64), 0, stream>>>(wq, bq, wk, bk, xm, qm, km);
  k_qkv<<<dim3(256), dim3(256), 0, stream>>>(x, wq, bq, wk, bk, wv, bv, qm, km, Q, Kf, Vf, u);
  k_unary<<<dim3(512), dim3(256), 0, stream>>>(u, Vf, ou);
  k_attn<<<dim3(512), dim3(512), 0, stream>>>(Q, Kf, Vf, ou, x, out);
}